// Round 1
// baseline (5003.586 us; speedup 1.0000x reference)
//
#include <hip/hip_runtime.h>
#include <hip/hip_bf16.h>

// Problem constants (match reference)
#define CDIM 1024
#define TLEN 2048
#define BATCH 2
#define NTOK 4096      // BATCH*TLEN
#define NHEAD 16
#define HDIM 64
#define NEXP 8
#define HID 4096
#define NSLOT 8192     // NTOK * TOPK

__device__ __forceinline__ float bf2f(unsigned short u) {
  return __uint_as_float(((unsigned int)u) << 16);
}
__device__ __forceinline__ unsigned short f2bf(float f) {
  unsigned int x = __float_as_uint(f);
  unsigned int r = (x + 0x7fffu + ((x >> 16) & 1u)) >> 16;
  return (unsigned short)r;
}
__device__ __forceinline__ void f4a(float4 v, float* a) {
  a[0] = v.x; a[1] = v.y; a[2] = v.z; a[3] = v.w;
}

// ---------------- RMSNorm: out[row] = in[row] * rsqrt(mean(in^2)+eps) * w ----
__global__ __launch_bounds__(256) void rmsnorm_k(const float* __restrict__ in,
                                                 const float* __restrict__ w,
                                                 float* __restrict__ out) {
  int row = blockIdx.x;
  int tid = threadIdx.x;  // 256 threads, 4 floats each = 1024
  float4 a = ((const float4*)(in + (size_t)row * CDIM))[tid];
  float ss = a.x * a.x + a.y * a.y + a.z * a.z + a.w * a.w;
#pragma unroll
  for (int off = 32; off > 0; off >>= 1) ss += __shfl_xor(ss, off);
  __shared__ float sred[4];
  if ((tid & 63) == 0) sred[tid >> 6] = ss;
  __syncthreads();
  float tot = sred[0] + sred[1] + sred[2] + sred[3];
  float inv = rsqrtf(tot * (1.0f / CDIM) + 1e-8f);
  float4 wv = ((const float4*)w)[tid];
  float4 o;
  o.x = a.x * inv * wv.x; o.y = a.y * inv * wv.y;
  o.z = a.z * inv * wv.z; o.w = a.w * inv * wv.w;
  ((float4*)(out + (size_t)row * CDIM))[tid] = o;
}

// ---------------- Generic fp32 GEMM: out = A[M,K] @ W[K,N] + bias (+resid) ---
// 64x64 tile, 256 threads, 4x4 per thread. M,N multiples of 64 here.
__global__ __launch_bounds__(256) void gemm_bias_k(
    const float* __restrict__ A, const float* __restrict__ W,
    const float* __restrict__ bias, const float* __restrict__ resid,
    float* __restrict__ out, int Kdim, int Nd) {
  __shared__ float As[16][68];  // As[k][m]
  __shared__ float Bs[16][68];  // Bs[k][n]
  int t = threadIdx.x;
  int tx = t & 15, ty = t >> 4;
  int m0 = blockIdx.y * 64, n0 = blockIdx.x * 64;
  int arow = t >> 2, ak = (t & 3) * 4;
  int brow = t >> 4, bc = (t & 15) * 4;
  float acc[4][4] = {};
  for (int k0 = 0; k0 < Kdim; k0 += 16) {
    float4 av = *(const float4*)(A + (size_t)(m0 + arow) * Kdim + k0 + ak);
    float4 bv = *(const float4*)(W + (size_t)(k0 + brow) * Nd + n0 + bc);
    __syncthreads();
    As[ak + 0][arow] = av.x; As[ak + 1][arow] = av.y;
    As[ak + 2][arow] = av.z; As[ak + 3][arow] = av.w;
    *(float4*)&Bs[brow][bc] = bv;
    __syncthreads();
#pragma unroll
    for (int kk = 0; kk < 16; kk++) {
      float as[4], bs[4];
      f4a(*(const float4*)&As[kk][ty * 4], as);
      f4a(*(const float4*)&Bs[kk][tx * 4], bs);
#pragma unroll
      for (int i = 0; i < 4; i++)
#pragma unroll
        for (int j = 0; j < 4; j++) acc[i][j] += as[i] * bs[j];
    }
  }
#pragma unroll
  for (int i = 0; i < 4; i++) {
    int m = m0 + ty * 4 + i;
#pragma unroll
    for (int j = 0; j < 4; j++) {
      int n = n0 + tx * 4 + j;
      float v = acc[i][j] + bias[n];
      if (resid) v += resid[(size_t)m * Nd + n];
      out[(size_t)m * Nd + n] = v;
    }
  }
}

// ---------------- Flash attention with ALiBi, 64x64 tiles ------------------
// q: [NTOK, CDIM] (col = h*64+d); kv: [NTOK, 2*CDIM] (K cols 0..1023, V 1024..)
__global__ __launch_bounds__(256) void attn_k(const float* __restrict__ q,
                                              const float* __restrict__ kv,
                                              float* __restrict__ y) {
  int qt = blockIdx.x, h = blockIdx.y, b = blockIdx.z;
  __shared__ float Qs[64][68];
  __shared__ float KPs[64][68];  // K tile, then reused for P
  __shared__ float Vs[64][68];
  int t = threadIdx.x, tx = t & 15, ty = t >> 4;
  int lrow = t >> 4, lcol = (t & 15) * 4;
  size_t qbase = (size_t)b * TLEN + (size_t)qt * 64;
#pragma unroll
  for (int it = 0; it < 4; it++) {
    int row = lrow + it * 16;
    *(float4*)&Qs[row][lcol] =
        *(const float4*)(q + (qbase + row) * CDIM + h * HDIM + lcol);
  }
  float m_i[4], l_i[4], o[4][4];
#pragma unroll
  for (int i = 0; i < 4; i++) {
    m_i[i] = -1e30f; l_i[i] = 0.f;
#pragma unroll
    for (int j = 0; j < 4; j++) o[i][j] = 0.f;
  }
  float slope = (float)(h + 1) * (1.0f / NHEAD);
  for (int kt = 0; kt <= qt; kt++) {
    size_t kbase = (size_t)b * TLEN + (size_t)kt * 64;
    float4 kreg[4], vreg[4];
#pragma unroll
    for (int it = 0; it < 4; it++) {
      int row = lrow + it * 16;
      kreg[it] = *(const float4*)(kv + (kbase + row) * (2 * CDIM) + h * HDIM + lcol);
      vreg[it] = *(const float4*)(kv + (kbase + row) * (2 * CDIM) + CDIM + h * HDIM + lcol);
    }
    __syncthreads();  // prior iter done reading KPs/Vs
#pragma unroll
    for (int it = 0; it < 4; it++) {
      int row = lrow + it * 16;
      *(float4*)&KPs[row][lcol] = kreg[it];
      *(float4*)&Vs[row][lcol] = vreg[it];
    }
    __syncthreads();
    float s[4][4] = {};
    for (int d = 0; d < HDIM; d += 4) {
      float qv[4][4], kvv[4][4];
#pragma unroll
      for (int i = 0; i < 4; i++) f4a(*(const float4*)&Qs[ty * 4 + i][d], qv[i]);
#pragma unroll
      for (int j = 0; j < 4; j++) f4a(*(const float4*)&KPs[tx * 4 + j][d], kvv[j]);
#pragma unroll
      for (int i = 0; i < 4; i++)
#pragma unroll
        for (int j = 0; j < 4; j++)
          s[i][j] += qv[i][0] * kvv[j][0] + qv[i][1] * kvv[j][1] +
                     qv[i][2] * kvv[j][2] + qv[i][3] * kvv[j][3];
    }
#pragma unroll
    for (int i = 0; i < 4; i++) {
      int qg = qt * 64 + ty * 4 + i;
      float sv[4], rowm = -1e30f;
#pragma unroll
      for (int j = 0; j < 4; j++) {
        int kg = kt * 64 + tx * 4 + j;
        float v = s[i][j] * 0.125f + slope * (float)(kg - qg);
        v = (kg <= qg) ? v : -1e30f;
        sv[j] = v;
        rowm = fmaxf(rowm, v);
      }
#pragma unroll
      for (int off = 1; off < 16; off <<= 1) rowm = fmaxf(rowm, __shfl_xor(rowm, off));
      float newm = fmaxf(m_i[i], rowm);
      float alpha = __expf(m_i[i] - newm);
      float rs = 0.f;
#pragma unroll
      for (int j = 0; j < 4; j++) {
        float p = __expf(sv[j] - newm);
        s[i][j] = p;
        rs += p;
      }
#pragma unroll
      for (int off = 1; off < 16; off <<= 1) rs += __shfl_xor(rs, off);
      l_i[i] = l_i[i] * alpha + rs;
      m_i[i] = newm;
#pragma unroll
      for (int j = 0; j < 4; j++) o[i][j] *= alpha;
    }
    __syncthreads();  // everyone done reading K from KPs
#pragma unroll
    for (int i = 0; i < 4; i++)
#pragma unroll
      for (int j = 0; j < 4; j++) KPs[ty * 4 + i][tx * 4 + j] = s[i][j];
    __syncthreads();
    for (int kk = 0; kk < 64; kk += 4) {
      float pr[4][4], vv[4][4];
#pragma unroll
      for (int i = 0; i < 4; i++) f4a(*(const float4*)&KPs[ty * 4 + i][kk], pr[i]);
#pragma unroll
      for (int u = 0; u < 4; u++) f4a(*(const float4*)&Vs[kk + u][tx * 4], vv[u]);
#pragma unroll
      for (int i = 0; i < 4; i++)
#pragma unroll
        for (int j = 0; j < 4; j++)
          o[i][j] += pr[i][0] * vv[0][j] + pr[i][1] * vv[1][j] +
                     pr[i][2] * vv[2][j] + pr[i][3] * vv[3][j];
    }
  }
#pragma unroll
  for (int i = 0; i < 4; i++) {
    float invl = 1.0f / l_i[i];
    size_t row = qbase + ty * 4 + i;
#pragma unroll
    for (int j = 0; j < 4; j++)
      y[row * CDIM + h * HDIM + tx * 4 + j] = o[i][j] * invl;
  }
}

// ---------------- Router: logits=h2@rw, top2 + softmax, count --------------
__global__ void zero_cnt_k(int* cnt) {
  if (threadIdx.x < NEXP) cnt[threadIdx.x] = 0;
}

__global__ __launch_bounds__(64) void router_k(const float* __restrict__ h2,
                                               const float* __restrict__ rw,
                                               int* __restrict__ sel_idx,
                                               float* __restrict__ sel_w,
                                               int* __restrict__ cnt) {
  int tok = blockIdx.x;
  int lane = threadIdx.x;  // 64
  float acc[NEXP] = {};
  for (int c = lane; c < CDIM; c += 64) {
    float hv = h2[(size_t)tok * CDIM + c];
    const float* r = rw + (size_t)c * NEXP;
#pragma unroll
    for (int e = 0; e < NEXP; e++) acc[e] += hv * r[e];
  }
#pragma unroll
  for (int e = 0; e < NEXP; e++)
#pragma unroll
    for (int off = 32; off > 0; off >>= 1) acc[e] += __shfl_xor(acc[e], off);
  if (lane == 0) {
    int i0 = 0; float l0 = acc[0];
    for (int e = 1; e < NEXP; e++) if (acc[e] > l0) { l0 = acc[e]; i0 = e; }
    int i1 = -1; float l1 = -1e30f;
    for (int e = 0; e < NEXP; e++)
      if (e != i0 && acc[e] > l1) { l1 = acc[e]; i1 = e; }
    float w0 = 1.f / (1.f + __expf(l1 - l0));
    sel_idx[2 * tok] = i0; sel_idx[2 * tok + 1] = i1;
    sel_w[2 * tok] = w0;   sel_w[2 * tok + 1] = 1.f - w0;
    atomicAdd(&cnt[i0], 1);
    atomicAdd(&cnt[i1], 1);
  }
}

__global__ void scan_k(const int* __restrict__ cnt, int* __restrict__ eoff,
                       int* __restrict__ cursor) {
  if (threadIdx.x == 0) {
    int s = 0;
    for (int e = 0; e < NEXP; e++) { eoff[e] = s; cursor[e] = s; s += cnt[e]; }
    eoff[NEXP] = s;
  }
}

__global__ __launch_bounds__(256) void gather_k(const int* __restrict__ sel_idx,
                                                const float* __restrict__ sel_w,
                                                int* __restrict__ cursor,
                                                int* __restrict__ gtok,
                                                float* __restrict__ gwv) {
  int t = blockIdx.x * blockDim.x + threadIdx.x;
  if (t >= NTOK) return;
#pragma unroll
  for (int k = 0; k < 2; k++) {
    int e = sel_idx[2 * t + k];
    int p = atomicAdd(&cursor[e], 1);
    gtok[p] = t;
    gwv[p] = sel_w[2 * t + k];
  }
}

// ---------------- MoE GEMM1: mid = bf16( silu(h2@gate) * (h2@up) ) ---------
__global__ __launch_bounds__(256) void moe_gemm1_k(
    const float* __restrict__ h2, const float* __restrict__ gate_w,
    const float* __restrict__ up_w, const int* __restrict__ cnt,
    const int* __restrict__ eoff, const int* __restrict__ gtok,
    unsigned short* __restrict__ mid) {
  int e = blockIdx.z, rt = blockIdx.y, ht = blockIdx.x;
  int ne = cnt[e];
  if (rt * 64 >= ne) return;
  int base = eoff[e];
  __shared__ float As[16][68], B1s[16][68], B2s[16][68];
  __shared__ int toks[64];
  int t = threadIdx.x, tx = t & 15, ty = t >> 4;
  if (t < 64) {
    int r = rt * 64 + t;
    toks[t] = (r < ne) ? gtok[base + r] : -1;
  }
  __syncthreads();
  const float* G = gate_w + (size_t)e * CDIM * HID;
  const float* U = up_w + (size_t)e * CDIM * HID;
  int n0 = ht * 64;
  int arow = t >> 2, ak = (t & 3) * 4;
  int brow = t >> 4, bc = (t & 15) * 4;
  int tokA = toks[arow];
  float acc1[4][4] = {}, acc2[4][4] = {};
  for (int k0 = 0; k0 < CDIM; k0 += 16) {
    float4 av = make_float4(0.f, 0.f, 0.f, 0.f);
    if (tokA >= 0) av = *(const float4*)(h2 + (size_t)tokA * CDIM + k0 + ak);
    float4 b1 = *(const float4*)(G + (size_t)(k0 + brow) * HID + n0 + bc);
    float4 b2 = *(const float4*)(U + (size_t)(k0 + brow) * HID + n0 + bc);
    __syncthreads();
    As[ak + 0][arow] = av.x; As[ak + 1][arow] = av.y;
    As[ak + 2][arow] = av.z; As[ak + 3][arow] = av.w;
    *(float4*)&B1s[brow][bc] = b1;
    *(float4*)&B2s[brow][bc] = b2;
    __syncthreads();
#pragma unroll
    for (int kk = 0; kk < 16; kk++) {
      float as[4], b1v[4], b2v[4];
      f4a(*(const float4*)&As[kk][ty * 4], as);
      f4a(*(const float4*)&B1s[kk][tx * 4], b1v);
      f4a(*(const float4*)&B2s[kk][tx * 4], b2v);
#pragma unroll
      for (int i = 0; i < 4; i++)
#pragma unroll
        for (int j = 0; j < 4; j++) {
          acc1[i][j] += as[i] * b1v[j];
          acc2[i][j] += as[i] * b2v[j];
        }
    }
  }
#pragma unroll
  for (int i = 0; i < 4; i++) {
    int r = rt * 64 + ty * 4 + i;
    if (r < ne) {
      size_t slot = (size_t)base + r;
#pragma unroll
      for (int j = 0; j < 4; j++) {
        float g = acc1[i][j], u = acc2[i][j];
        float val = g / (1.f + __expf(-g)) * u;  // silu(g)*u
        mid[slot * HID + n0 + tx * 4 + j] = f2bf(val);
      }
    }
  }
}

// ---------------- MoE GEMM2: out += w * (mid @ down_e), fp32 atomics -------
__global__ __launch_bounds__(256) void moe_gemm2_k(
    const unsigned short* __restrict__ mid, const float* __restrict__ down_w,
    const int* __restrict__ cnt, const int* __restrict__ eoff,
    const int* __restrict__ gtok, const float* __restrict__ gwv,
    float* __restrict__ out) {
  int e = blockIdx.z, rt = blockIdx.y, ct = blockIdx.x;
  int ne = cnt[e];
  if (rt * 64 >= ne) return;
  int base = eoff[e];
  __shared__ float As[16][68], Bs[16][68];
  int t = threadIdx.x, tx = t & 15, ty = t >> 4;
  const float* D = down_w + (size_t)e * HID * CDIM;
  int n0 = ct * 64;
  int arow = t >> 2, ak = (t & 3) * 4;
  int brow = t >> 4, bc = (t & 15) * 4;
  int rA = rt * 64 + arow;
  bool validA = rA < ne;
  size_t slotA = (size_t)base + rA;
  float acc[4][4] = {};
  for (int k0 = 0; k0 < HID; k0 += 16) {
    float4 av = make_float4(0.f, 0.f, 0.f, 0.f);
    if (validA) {
      ushort4 u = *(const ushort4*)(mid + slotA * HID + k0 + ak);
      av.x = bf2f(u.x); av.y = bf2f(u.y); av.z = bf2f(u.z); av.w = bf2f(u.w);
    }
    float4 bv = *(const float4*)(D + (size_t)(k0 + brow) * CDIM + n0 + bc);
    __syncthreads();
    As[ak + 0][arow] = av.x; As[ak + 1][arow] = av.y;
    As[ak + 2][arow] = av.z; As[ak + 3][arow] = av.w;
    *(float4*)&Bs[brow][bc] = bv;
    __syncthreads();
#pragma unroll
    for (int kk = 0; kk < 16; kk++) {
      float as[4], bs[4];
      f4a(*(const float4*)&As[kk][ty * 4], as);
      f4a(*(const float4*)&Bs[kk][tx * 4], bs);
#pragma unroll
      for (int i = 0; i < 4; i++)
#pragma unroll
        for (int j = 0; j < 4; j++) acc[i][j] += as[i] * bs[j];
    }
  }
#pragma unroll
  for (int i = 0; i < 4; i++) {
    int r = rt * 64 + ty * 4 + i;
    if (r < ne) {
      int tok = gtok[base + r];
      float w = gwv[base + r];
#pragma unroll
      for (int j = 0; j < 4; j++)
        atomicAdd(&out[(size_t)tok * CDIM + n0 + tx * 4 + j], w * acc[i][j]);
    }
  }
}

// ---------------------------------------------------------------------------
extern "C" void kernel_launch(void* const* d_in, const int* in_sizes, int n_in,
                              void* d_out, int out_size, void* d_ws, size_t ws_size,
                              hipStream_t stream) {
  (void)in_sizes; (void)n_in; (void)out_size; (void)ws_size;
  const float* x   = (const float*)d_in[0];
  const float* anw = (const float*)d_in[1];
  const float* fnw = (const float*)d_in[2];
  const float* qw  = (const float*)d_in[3];
  const float* qb  = (const float*)d_in[4];
  const float* kvw = (const float*)d_in[5];
  const float* kvb = (const float*)d_in[6];
  const float* ow  = (const float*)d_in[7];
  const float* ob  = (const float*)d_in[8];
  const float* rw  = (const float*)d_in[9];
  const float* gw  = (const float*)d_in[10];
  const float* uw  = (const float*)d_in[11];
  const float* dw  = (const float*)d_in[12];
  float* out = (float*)d_out;

  // Workspace layout (~97 MB):
  //   [0,64K)   sel_idx  int[8192]
  //   [64K,128K) sel_w   float[8192]
  //   [128K,..) cnt[8] / eoff[9] / cursor[8]
  //   [192K,..) gtok int[8192]
  //   [256K,..) gwv  float[8192]
  //   [1M, 17M)  buf0: h1 then y
  //   [17M,33M)  buf1: q then h2
  //   [33M,97M)  buf2: kv [NTOK,2048] fp32, then mid bf16 [8192,4096]
  char* ws = (char*)d_ws;
  int*   sel_idx = (int*)(ws);
  float* sel_w   = (float*)(ws + (64 << 10));
  int*   cnt     = (int*)(ws + (128 << 10));
  int*   eoff    = cnt + 16;
  int*   cursor  = cnt + 32;
  int*   gtok    = (int*)(ws + (192 << 10));
  float* gwv     = (float*)(ws + (256 << 10));
  float* buf0 = (float*)(ws + (1 << 20));
  float* buf1 = buf0 + (size_t)NTOK * CDIM;
  float* buf2 = buf1 + (size_t)NTOK * CDIM;
  unsigned short* mid = (unsigned short*)buf2;

  zero_cnt_k<<<1, 64, 0, stream>>>(cnt);
  // h1 = rmsnorm(x) * attn_norm_w
  rmsnorm_k<<<NTOK, 256, 0, stream>>>(x, anw, buf0);
  // q = h1@qw + qb ; kv = h1@kvw + kvb
  gemm_bias_k<<<dim3(16, 64), 256, 0, stream>>>(buf0, qw, qb, nullptr, buf1, CDIM, CDIM);
  gemm_bias_k<<<dim3(32, 64), 256, 0, stream>>>(buf0, kvw, kvb, nullptr, buf2, CDIM, 2 * CDIM);
  // y = attention(q, k, v)  (into buf0; h1 dead)
  attn_k<<<dim3(32, NHEAD, BATCH), 256, 0, stream>>>(buf1, buf2, buf0);
  // out = x + y@ow + ob
  gemm_bias_k<<<dim3(16, 64), 256, 0, stream>>>(buf0, ow, ob, x, out, CDIM, CDIM);
  // h2 = rmsnorm(out) * ffn_norm_w  (into buf1; q dead)
  rmsnorm_k<<<NTOK, 256, 0, stream>>>(out, fnw, buf1);
  // routing
  router_k<<<NTOK, 64, 0, stream>>>(buf1, rw, sel_idx, sel_w, cnt);
  scan_k<<<1, 64, 0, stream>>>(cnt, eoff, cursor);
  gather_k<<<16, 256, 0, stream>>>(sel_idx, sel_w, cursor, gtok, gwv);
  // MoE
  moe_gemm1_k<<<dim3(HID / 64, 64, NEXP), 256, 0, stream>>>(buf1, gw, uw, cnt, eoff, gtok, mid);
  moe_gemm2_k<<<dim3(CDIM / 64, 64, NEXP), 256, 0, stream>>>(mid, dw, cnt, eoff, gtok, gwv, out);
}